// Round 11
// baseline (303.735 us; speedup 1.0000x reference)
//
#include <hip/hip_runtime.h>
#include <math.h>

#define HW 4096   // H*W = 64*64; B=4, C=64, H=W=64, L=4096

typedef short bf16x8 __attribute__((ext_vector_type(8)));
typedef float floatx4 __attribute__((ext_vector_type(4)));
typedef unsigned short ushort8 __attribute__((ext_vector_type(8)));

__device__ __forceinline__ unsigned short f2bf_rne(float x) {
    unsigned int u = __float_as_uint(x);
    unsigned int r = (u + 0x7FFFu + ((u >> 16) & 1u)) >> 16;
    return (unsigned short)r;
}
__device__ __forceinline__ float bf2f(unsigned short h) {
    return __uint_as_float(((unsigned int)h) << 16);
}

// async global->LDS, 16 B per lane; LDS dest is wave-uniform base + lane*16.
__device__ __forceinline__ void gload_lds16(const void* gptr, void* lptr) {
    auto g = (const __attribute__((address_space(1))) unsigned int*)(unsigned long long)(gptr);
    auto l = (__attribute__((address_space(3))) unsigned int*)(unsigned int)(unsigned long long)(lptr);
    __builtin_amdgcn_global_load_lds(g, l, 16, 0, 0);
}

// ---------------- prep: split fp32 -> bf16 (hi,lo), transpose to [p][c], ------
// fused per-pixel squared norms. Aq[b][p] = [Qh|Qh|Ql], Bq[b][p] = [Kh|Kl|Kh].
// Vectorized 16-B stores (each thread owns 16 contiguous c's).
__global__ __launch_bounds__(256)
void prep_kernel(const float* __restrict__ Q, const float* __restrict__ K,
                 unsigned short* __restrict__ Aq, unsigned short* __restrict__ Bq,
                 float* __restrict__ pix2q, float* __restrict__ pix2k) {
    __shared__ float sT[64][65];
    const int tid = threadIdx.x;
    const int p0 = blockIdx.x * 64;
    const int b = blockIdx.y;
    const int pp = tid >> 2, qt = tid & 3;
    const size_t base = ((size_t)b * 4096 + p0 + pp) * 192;

#pragma unroll
    for (int it = 0; it < 16; ++it) {
        int idx = it * 256 + tid;
        int c = idx >> 6, x = idx & 63;
        sT[c][x] = Q[((size_t)b * 64 + c) * HW + p0 + x];
    }
    __syncthreads();
    {
        float sq = 0.f;
        ushort8 h0, h1, l0, l1;
#pragma unroll
        for (int i = 0; i < 16; ++i) {
            float x = sT[qt * 16 + i][pp];
            sq = fmaf(x, x, sq);
            unsigned short h = f2bf_rne(x);
            unsigned short l = f2bf_rne(x - bf2f(h));
            if (i < 8) { h0[i] = h; l0[i] = l; } else { h1[i - 8] = h; l1[i - 8] = l; }
        }
        *(ushort8*)&Aq[base + qt * 16]           = h0;
        *(ushort8*)&Aq[base + qt * 16 + 8]       = h1;
        *(ushort8*)&Aq[base + 64 + qt * 16]      = h0;
        *(ushort8*)&Aq[base + 64 + qt * 16 + 8]  = h1;
        *(ushort8*)&Aq[base + 128 + qt * 16]     = l0;
        *(ushort8*)&Aq[base + 128 + qt * 16 + 8] = l1;
        sq += __shfl_xor(sq, 1, 64);
        sq += __shfl_xor(sq, 2, 64);
        if (qt == 0) pix2q[(b << 12) + p0 + pp] = sq;
    }
    __syncthreads();

#pragma unroll
    for (int it = 0; it < 16; ++it) {
        int idx = it * 256 + tid;
        int c = idx >> 6, x = idx & 63;
        sT[c][x] = K[((size_t)b * 64 + c) * HW + p0 + x];
    }
    __syncthreads();
    {
        float sk = 0.f;
        ushort8 h0, h1, l0, l1;
#pragma unroll
        for (int i = 0; i < 16; ++i) {
            float x = sT[qt * 16 + i][pp];
            sk = fmaf(x, x, sk);
            unsigned short h = f2bf_rne(x);
            unsigned short l = f2bf_rne(x - bf2f(h));
            if (i < 8) { h0[i] = h; l0[i] = l; } else { h1[i - 8] = h; l1[i - 8] = l; }
        }
        *(ushort8*)&Bq[base + qt * 16]           = h0;
        *(ushort8*)&Bq[base + qt * 16 + 8]       = h1;
        *(ushort8*)&Bq[base + 64 + qt * 16]      = l0;
        *(ushort8*)&Bq[base + 64 + qt * 16 + 8]  = l1;
        *(ushort8*)&Bq[base + 128 + qt * 16]     = h0;
        *(ushort8*)&Bq[base + 128 + qt * 16 + 8] = h1;
        sk += __shfl_xor(sk, 1, 64);
        sk += __shfl_xor(sk, 2, 64);
        if (qt == 0) pix2k[(b << 12) + p0 + pp] = sk;
    }
}

// ---------------- patch reciprocal norms: 1/max(sqrt(3x3 box sum), 1e-12) ----
__global__ void patchnorm_kernel(const float* __restrict__ pix2q, const float* __restrict__ pix2k,
                                 float* __restrict__ rnq, float* __restrict__ rnk) {
    int idx = blockIdx.x * 256 + threadIdx.x;   // b*4096 + p
    int b = idx >> 12, p = idx & 4095;
    int py = p >> 6, px = p & 63;
    float sq = 0.f, sk = 0.f;
    for (int dy = -1; dy <= 1; ++dy)
        for (int dx = -1; dx <= 1; ++dx) {
            int yy = py + dy, xx = px + dx;
            if ((unsigned)yy < 64u && (unsigned)xx < 64u) {
                int o = (b << 12) + (yy << 6) + xx;
                sq += pix2q[o];
                sk += pix2k[o];
            }
        }
    rnq[idx] = 1.f / fmaxf(sqrtf(sq), 1e-12f);
    rnk[idx] = 1.f / fmaxf(sqrtf(sk), 1e-12f);
}

// ---------------- fused MFMA GEMM (K=576: y-3sum in K) + x-3sum + argmax -----
// 256q x 128k tile, 512 threads (8 waves: wm=wid&3 q-band, wn=wid>>2 k-half).
// Per seg: stage A slab 384 rows (48 KB) + B slab 256 rows (32 KB) once; the 3
// dy variants are LDS row windows. 80 KB LDS -> 2 blocks/CU = 4 waves/SIMD
// (2x R10). 6 main barriers; 96 MFMAs/wave per barrier pair.
__global__ __launch_bounds__(512, 4)
void gemm_fused_kernel(const unsigned short* __restrict__ Aq, const unsigned short* __restrict__ Bq,
                       const float* __restrict__ rnkA,
                       float* __restrict__ part_val, int* __restrict__ part_arg) {
    __shared__ __align__(16) char smem[81920];   // A slab 48K | B slab 32K; epi Csh[64][133]
    const int tid = threadIdx.x;
    const int lane = tid & 63, wid = tid >> 6;
    const int m15 = lane & 15, quad = lane >> 4;
    const int wm = wid & 3, wn = wid >> 2;       // q band (0..3), k half (0..1)
    const int k0 = blockIdx.x * 128;
    const int q0 = blockIdx.y * 256;
    const int b = blockIdx.z;
    const char* Aqb = (const char*)(Aq + (size_t)b * 4096 * 192);
    const char* Bqb = (const char*)(Bq + (size_t)b * 4096 * 192);
    const bool aInt = (q0 >= 64) && (q0 + 320 <= 4096);   // A slab fully in-image
    const bool bInt = (k0 >= 64) && (k0 + 192 <= 4096);

    floatx4 acc[4][4];
#pragma unroll
    for (int i = 0; i < 4; ++i)
#pragma unroll
        for (int j = 0; j < 4; ++j) acc[i][j] = (floatx4)0.f;

    for (int seg = 0; seg < 3; ++seg) {
        // slot = row*8 + pos, pos = G ^ (row&7): frag b128 reads 2-way aliased (free)
        const char* ab = Aqb + (size_t)(q0 - 64) * 384 + seg * 128;
        const char* bb = Bqb + (size_t)(k0 - 64) * 384 + seg * 128;
        if (aInt) {
#pragma unroll
            for (int it = 0; it < 6; ++it) {     // 384 rows * 8 = 3072 slots
                int slot = it * 512 + tid;
                int row = slot >> 3, pos = slot & 7;
                int G = pos ^ (row & 7);
                gload_lds16(ab + (size_t)row * 384 + G * 16, smem + slot * 16);
            }
        } else {
#pragma unroll
            for (int it = 0; it < 6; ++it) {
                int slot = it * 512 + tid;
                int row = slot >> 3, pos = slot & 7;
                int G = pos ^ (row & 7);
                uint4 v = make_uint4(0u, 0u, 0u, 0u);
                if ((unsigned)(q0 - 64 + row) < 4096u)
                    v = *(const uint4*)(ab + (size_t)row * 384 + G * 16);
                *(uint4*)(smem + slot * 16) = v;
            }
        }
        if (bInt) {
#pragma unroll
            for (int it = 0; it < 4; ++it) {     // 256 rows * 8 = 2048 slots
                int slot = it * 512 + tid;
                int row = slot >> 3, pos = slot & 7;
                int G = pos ^ (row & 7);
                gload_lds16(bb + (size_t)row * 384 + G * 16, smem + 49152 + slot * 16);
            }
        } else {
#pragma unroll
            for (int it = 0; it < 4; ++it) {
                int slot = it * 512 + tid;
                int row = slot >> 3, pos = slot & 7;
                int G = pos ^ (row & 7);
                uint4 v = make_uint4(0u, 0u, 0u, 0u);
                if ((unsigned)(k0 - 64 + row) < 4096u)
                    v = *(const uint4*)(bb + (size_t)row * 384 + G * 16);
                *(uint4*)(smem + 49152 + slot * 16) = v;
            }
        }
        __syncthreads();   // drains vmcnt incl. global_load_lds

#pragma unroll
        for (int dy = 0; dy < 3; ++dy) {
#pragma unroll
            for (int kk = 0; kk < 2; ++kk) {
                bf16x8 af[4], bfr[4];
#pragma unroll
                for (int mt = 0; mt < 4; ++mt) {
                    int row = dy * 64 + wm * 64 + mt * 16 + m15;     // 0..383
                    int pos = (kk * 4 + quad) ^ (row & 7);
                    af[mt] = *(const bf16x8*)(smem + (row * 8 + pos) * 16);
                }
#pragma unroll
                for (int nt = 0; nt < 4; ++nt) {
                    int row = dy * 64 + wn * 64 + nt * 16 + m15;     // 0..255
                    int pos = (kk * 4 + quad) ^ (row & 7);
                    bfr[nt] = *(const bf16x8*)(smem + 49152 + (row * 8 + pos) * 16);
                }
#pragma unroll
                for (int mt = 0; mt < 4; ++mt)
#pragma unroll
                    for (int nt = 0; nt < 4; ++nt)
                        acc[mt][nt] = __builtin_amdgcn_mfma_f32_16x16x32_bf16(
                            af[mt], bfr[nt], acc[mt][nt], 0, 0, 0);
            }
        }
        __syncthreads();   // slabs dead before next seg overwrites
    }

    // ---- epilogue: four 64-row phases; x-3sum + max/argmax over the 128-k tile ----
    float* Csh = (float*)smem;               // [64][133]
    const int r = tid >> 3;                  // q row within band (0..63) = qx
    const int sub = tid & 7;                 // 16-col chunk
    const int c0 = sub * 16;
    const float4 zero4 = make_float4(0.f, 0.f, 0.f, 0.f);

#pragma unroll
    for (int h = 0; h < 4; ++h) {
        if (h) __syncthreads();              // prior phase readers done before overwrite
        if (wm == h) {
#pragma unroll
            for (int mt = 0; mt < 4; ++mt)
#pragma unroll
                for (int nt = 0; nt < 4; ++nt)
#pragma unroll
                    for (int j = 0; j < 4; ++j)
                        Csh[(mt * 16 + quad * 4 + j) * 133 + wn * 64 + nt * 16 + m15] =
                            acc[mt][nt][j];
        }
        __syncthreads();

        const bool qm = r > 0;               // qx>0: diag- allowed
        const bool qp = r < 63;              // qx<63: diag+ allowed
        const float* rC = Csh + r * 133;
        const float* rM = rC - 133;
        const float* rP = rC + 133;
        float4 prevm = (qm && c0 > 0) ? *(const float4*)&rM[c0 - 4] : zero4;
        float4 rpj   = qp ? *(const float4*)&rP[c0] : zero4;
        float bv = -INFINITY;
        int ba = 0;
#pragma unroll
        for (int j = 0; j < 4; ++j) {
            int c = c0 + 4 * j;
            float4 cen = *(const float4*)&rC[c];
            float4 rm4 = qm ? *(const float4*)&rM[c] : zero4;
            float4 rp1 = (qp && (c + 4) < 128) ? *(const float4*)&rP[c + 4] : zero4;
            float4 o;
            o.x = cen.x + (((c & 63) != 0) ? prevm.w : 0.f) + rpj.y;
            o.y = cen.y + rm4.x + rpj.z;
            o.z = cen.z + rm4.y + rpj.w;
            o.w = cen.w + rm4.z + ((((c + 3) & 63) != 63) ? rp1.x : 0.f);
            float4 rk = *(const float4*)&rnkA[(b << 12) + k0 + c];
            // ascending k + strict > = first-occurrence argmax
            float v0 = o.x * rk.x; if (v0 > bv) { bv = v0; ba = k0 + c + 0; }
            float v1 = o.y * rk.y; if (v1 > bv) { bv = v1; ba = k0 + c + 1; }
            float v2 = o.z * rk.z; if (v2 > bv) { bv = v2; ba = k0 + c + 2; }
            float v3 = o.w * rk.w; if (v3 > bv) { bv = v3; ba = k0 + c + 3; }
            prevm = rm4;
            rpj = rp1;
        }
        // merge sub pairs (c0 and c0+16) -> one slot per 32-col quarter; lower k wins ties
        {
            float ov = __shfl_xor(bv, 1, 64);
            int oa = __shfl_xor(ba, 1, 64);
            if (ov > bv || (ov == bv && oa < ba)) { bv = ov; ba = oa; }
        }
        if ((sub & 1) == 0) {
            int q = q0 + h * 64 + r;
            int sidx = blockIdx.x * 4 + (sub >> 1);   // ascending-k slot order
            part_val[(((b << 7) + sidx) << 12) + q] = bv;
            part_arg[(((b << 7) + sidx) << 12) + q] = ba;
        }
    }
}

// ---------------- gather + fold, fused combine (128 k-slot partials) ---------
__global__ __launch_bounds__(256)
void gatherS_kernel(const float* __restrict__ V,
                    const float* __restrict__ part_val, const int* __restrict__ part_arg,
                    const float* __restrict__ rnqA,
                    float* __restrict__ S_out, float* __restrict__ T_out) {
    __shared__ int sArg[192];
    const int y = blockIdx.x, b = blockIdx.y;
    const int tid = threadIdx.x;
    if (tid < 192) {
        int r = tid >> 6, x = tid & 63;
        int yy = y - 1 + r;
        int a = 0;
        if ((unsigned)yy < 64u) {
            int base = (b << 19) + (yy << 6) + x;   // part[(b*128+s)][q]
            float bv = -INFINITY; int ba = 0;
#pragma unroll 8
            for (int s = 0; s < 128; ++s) {   // ascending s = ascending k: first max wins
                float v = part_val[base + (s << 12)];
                int aa = part_arg[base + (s << 12)];
                if (v > bv) { bv = v; ba = aa; }
            }
            a = ba;
            if (r == 1) {
                int idx = (b << 12) + (yy << 6) + x;
                S_out[idx] = bv * rnqA[idx];
            }
        }
        sArg[tid] = a;
    }
    __syncthreads();

    const int x = tid & 63, cq = tid >> 6;
    int off[9];
#pragma unroll
    for (int t = 0; t < 9; ++t) {
        int dy = t / 3 - 1, dx = t % 3 - 1;
        int qy = y - dy, qx = x - dx;
        int o = -1;
        if ((unsigned)qy < 64u && (unsigned)qx < 64u) {
            int a = sArg[(1 - dy) * 64 + qx];
            int sy = (a >> 6) + dy, sx = (a & 63) + dx;
            if ((unsigned)sy < 64u && (unsigned)sx < 64u) o = (sy << 6) + sx;
        }
        off[t] = o;
    }
    const float* Vb = V + (size_t)b * 64 * HW;
    float* Tb = T_out + (size_t)b * 64 * HW + (y << 6) + x;
    for (int ci = 0; ci < 16; ++ci) {
        int c = cq * 16 + ci;
        const float* Vc = Vb + (size_t)c * HW;
        float acc = 0.f;
#pragma unroll
        for (int t = 0; t < 9; ++t)
            acc += (off[t] >= 0) ? Vc[off[t]] : 0.f;
        Tb[(size_t)c * HW] = acc * (1.f / 9.f);
    }
}

extern "C" void kernel_launch(void* const* d_in, const int* in_sizes, int n_in,
                              void* d_out, int out_size, void* d_ws, size_t ws_size,
                              hipStream_t stream) {
    const float* V = (const float*)d_in[0];
    const float* K = (const float*)d_in[1];
    const float* Q = (const float*)d_in[2];
    float* S_out = (float*)d_out;            // 4*4096
    float* T_out = S_out + 4 * HW;           // 4*64*4096

    char* ws = (char*)d_ws;
    float* pix2q = (float*)(ws + 0);                 // 64 KB
    float* pix2k = (float*)(ws + 65536);
    float* rnq   = (float*)(ws + 131072);
    float* rnk   = (float*)(ws + 196608);
    float* part_val = (float*)(ws + 262144);         // 4*128*4096 f = 8 MB
    int*   part_arg = (int*)(ws + 8650752);          // 8 MB
    unsigned short* Aq = (unsigned short*)(ws + 17039360);   // 4*4096*192 bf16 = 6 MiB
    unsigned short* Bq = (unsigned short*)(ws + 23330816);   // 6 MiB

    prep_kernel<<<dim3(64, 4), 256, 0, stream>>>(Q, K, Aq, Bq, pix2q, pix2k);
    patchnorm_kernel<<<64, 256, 0, stream>>>(pix2q, pix2k, rnq, rnk);
    gemm_fused_kernel<<<dim3(32, 16, 4), 512, 0, stream>>>(Aq, Bq, rnk, part_val, part_arg);
    gatherS_kernel<<<dim3(64, 4), 256, 0, stream>>>(V, part_val, part_arg, rnq, S_out, T_out);
}

// Round 12
// 286.453 us; speedup vs baseline: 1.0603x; 1.0603x over previous
//
#include <hip/hip_runtime.h>
#include <math.h>

#define HW 4096   // H*W = 64*64; B=4, C=64, H=W=64, L=4096

typedef short bf16x8 __attribute__((ext_vector_type(8)));
typedef float floatx4 __attribute__((ext_vector_type(4)));
typedef unsigned short ushort8 __attribute__((ext_vector_type(8)));

__device__ __forceinline__ unsigned short f2bf_rne(float x) {
    unsigned int u = __float_as_uint(x);
    unsigned int r = (u + 0x7FFFu + ((u >> 16) & 1u)) >> 16;
    return (unsigned short)r;
}
__device__ __forceinline__ float bf2f(unsigned short h) {
    return __uint_as_float(((unsigned int)h) << 16);
}

// async global->LDS, 16 B per lane; LDS dest is wave-uniform base + lane*16.
__device__ __forceinline__ void gload_lds16(const void* gptr, void* lptr) {
    auto g = (const __attribute__((address_space(1))) unsigned int*)(unsigned long long)(gptr);
    auto l = (__attribute__((address_space(3))) unsigned int*)(unsigned int)(unsigned long long)(lptr);
    __builtin_amdgcn_global_load_lds(g, l, 16, 0, 0);
}

// ---------------- prep: split fp32 -> bf16 (hi,lo), transpose, COMPACT layout --
// Aq[b][p] = [Qh(64) | Ql(64)]  (128 shorts, 256 B row)
// Bq[b][p] = [Kh(64) | Kl(64)]
// fused per-pixel squared norms.
__global__ __launch_bounds__(256)
void prep_kernel(const float* __restrict__ Q, const float* __restrict__ K,
                 unsigned short* __restrict__ Aq, unsigned short* __restrict__ Bq,
                 float* __restrict__ pix2q, float* __restrict__ pix2k) {
    __shared__ float sT[64][65];
    const int tid = threadIdx.x;
    const int p0 = blockIdx.x * 64;
    const int b = blockIdx.y;
    const int pp = tid >> 2, qt = tid & 3;
    const size_t base = ((size_t)b * 4096 + p0 + pp) * 128;

#pragma unroll
    for (int it = 0; it < 16; ++it) {
        int idx = it * 256 + tid;
        int c = idx >> 6, x = idx & 63;
        sT[c][x] = Q[((size_t)b * 64 + c) * HW + p0 + x];
    }
    __syncthreads();
    {
        float sq = 0.f;
        ushort8 h0, h1, l0, l1;
#pragma unroll
        for (int i = 0; i < 16; ++i) {
            float x = sT[qt * 16 + i][pp];
            sq = fmaf(x, x, sq);
            unsigned short h = f2bf_rne(x);
            unsigned short l = f2bf_rne(x - bf2f(h));
            if (i < 8) { h0[i] = h; l0[i] = l; } else { h1[i - 8] = h; l1[i - 8] = l; }
        }
        *(ushort8*)&Aq[base + qt * 16]          = h0;
        *(ushort8*)&Aq[base + qt * 16 + 8]      = h1;
        *(ushort8*)&Aq[base + 64 + qt * 16]     = l0;
        *(ushort8*)&Aq[base + 64 + qt * 16 + 8] = l1;
        sq += __shfl_xor(sq, 1, 64);
        sq += __shfl_xor(sq, 2, 64);
        if (qt == 0) pix2q[(b << 12) + p0 + pp] = sq;
    }
    __syncthreads();

#pragma unroll
    for (int it = 0; it < 16; ++it) {
        int idx = it * 256 + tid;
        int c = idx >> 6, x = idx & 63;
        sT[c][x] = K[((size_t)b * 64 + c) * HW + p0 + x];
    }
    __syncthreads();
    {
        float sk = 0.f;
        ushort8 h0, h1, l0, l1;
#pragma unroll
        for (int i = 0; i < 16; ++i) {
            float x = sT[qt * 16 + i][pp];
            sk = fmaf(x, x, sk);
            unsigned short h = f2bf_rne(x);
            unsigned short l = f2bf_rne(x - bf2f(h));
            if (i < 8) { h0[i] = h; l0[i] = l; } else { h1[i - 8] = h; l1[i - 8] = l; }
        }
        *(ushort8*)&Bq[base + qt * 16]          = h0;
        *(ushort8*)&Bq[base + qt * 16 + 8]      = h1;
        *(ushort8*)&Bq[base + 64 + qt * 16]     = l0;
        *(ushort8*)&Bq[base + 64 + qt * 16 + 8] = l1;
        sk += __shfl_xor(sk, 1, 64);
        sk += __shfl_xor(sk, 2, 64);
        if (qt == 0) pix2k[(b << 12) + p0 + pp] = sk;
    }
}

// ---------------- patch reciprocal norms: 1/max(sqrt(3x3 box sum), 1e-12) ----
__global__ void patchnorm_kernel(const float* __restrict__ pix2q, const float* __restrict__ pix2k,
                                 float* __restrict__ rnq, float* __restrict__ rnk) {
    int idx = blockIdx.x * 256 + threadIdx.x;   // b*4096 + p
    int b = idx >> 12, p = idx & 4095;
    int py = p >> 6, px = p & 63;
    float sq = 0.f, sk = 0.f;
    for (int dy = -1; dy <= 1; ++dy)
        for (int dx = -1; dx <= 1; ++dx) {
            int yy = py + dy, xx = px + dx;
            if ((unsigned)yy < 64u && (unsigned)xx < 64u) {
                int o = (b << 12) + (yy << 6) + xx;
                sq += pix2q[o];
                sk += pix2k[o];
            }
        }
    rnq[idx] = 1.f / fmaxf(sqrtf(sq), 1e-12f);
    rnk[idx] = 1.f / fmaxf(sqrtf(sk), 1e-12f);
}

// ---------------- fused MFMA GEMM (K=576 via 3 pairs x 3 dy) + x-3sum + argmax
// 256q x 256k block, 512 threads (8 waves: wm=wid&3 q band, wn=wid>>2 k half).
// D = Qh·Kh + Qh·Kl + Ql·Kh. Three persistent 48 KB slabs (384 rows x 64 cols):
// SQh, SKh, and a floating region staged Kl then Ql. 4 slab stages total,
// 3 main barriers, 18 MFMA phases (576 MFMAs/wave). 144 KB LDS -> 1 block/CU,
// 2 waves/SIMD (the honest occupancy; >2 spills — R8/R11 lesson).
__global__ __launch_bounds__(512, 2)
void gemm_fused_kernel(const unsigned short* __restrict__ Aq, const unsigned short* __restrict__ Bq,
                       const float* __restrict__ rnkA,
                       float* __restrict__ part_val, int* __restrict__ part_arg) {
    __shared__ __align__(16) char smem[147456];  // SQh|SKh|float (3x48K); epi Csh[64][264]
    const int tid = threadIdx.x;
    const int lane = tid & 63, wid = tid >> 6;
    const int m15 = lane & 15, quad = lane >> 4;
    const int wm = wid & 3, wn = wid >> 2;       // q band (0..3), k half (0..1)
    const int k0 = blockIdx.x * 256;
    const int q0 = blockIdx.y * 256;
    const int b = blockIdx.z;
    const char* Ab = (const char*)(Aq + (size_t)b * 4096 * 128);
    const char* Bb = (const char*)(Bq + (size_t)b * 4096 * 128);
    const bool aInt = (q0 >= 64) && (q0 + 320 <= 4096);
    const bool bInt = (k0 >= 64) && (k0 + 320 <= 4096);
    char* SQh = smem;
    char* SKh = smem + 49152;
    char* SFl = smem + 98304;

    floatx4 acc[4][8];
#pragma unroll
    for (int i = 0; i < 4; ++i)
#pragma unroll
        for (int j = 0; j < 8; ++j) acc[i][j] = (floatx4)0.f;

    // stage a 384-row slab (rows base-64..base+319, 64-col half colOff bytes)
    auto stageA = [&](int colOff, char* dst) {
        if (aInt) {
#pragma unroll
            for (int it = 0; it < 6; ++it) {
                int slot = it * 512 + tid;
                int row = slot >> 3, pos = slot & 7;
                int G = pos ^ (row & 7);
                gload_lds16(Ab + (size_t)(q0 - 64 + row) * 256 + colOff + G * 16, dst + slot * 16);
            }
        } else {
#pragma unroll
            for (int it = 0; it < 6; ++it) {
                int slot = it * 512 + tid;
                int row = slot >> 3, pos = slot & 7;
                int G = pos ^ (row & 7);
                int gr = q0 - 64 + row;
                uint4 v = make_uint4(0u, 0u, 0u, 0u);
                if ((unsigned)gr < 4096u) v = *(const uint4*)(Ab + (size_t)gr * 256 + colOff + G * 16);
                *(uint4*)(dst + slot * 16) = v;
            }
        }
    };
    auto stageB = [&](int colOff, char* dst) {
        if (bInt) {
#pragma unroll
            for (int it = 0; it < 6; ++it) {
                int slot = it * 512 + tid;
                int row = slot >> 3, pos = slot & 7;
                int G = pos ^ (row & 7);
                gload_lds16(Bb + (size_t)(k0 - 64 + row) * 256 + colOff + G * 16, dst + slot * 16);
            }
        } else {
#pragma unroll
            for (int it = 0; it < 6; ++it) {
                int slot = it * 512 + tid;
                int row = slot >> 3, pos = slot & 7;
                int G = pos ^ (row & 7);
                int gr = k0 - 64 + row;
                uint4 v = make_uint4(0u, 0u, 0u, 0u);
                if ((unsigned)gr < 4096u) v = *(const uint4*)(Bb + (size_t)gr * 256 + colOff + G * 16);
                *(uint4*)(dst + slot * 16) = v;
            }
        }
    };
    // one pair: 3 dy x 2 kk x (4 mt x 8 nt) MFMAs
    auto runPair = [&](const char* As, const char* Bs) {
#pragma unroll
        for (int dy = 0; dy < 3; ++dy)
#pragma unroll
            for (int kk = 0; kk < 2; ++kk) {
                bf16x8 af[4];
#pragma unroll
                for (int mt = 0; mt < 4; ++mt) {
                    int row = dy * 64 + wm * 64 + mt * 16 + m15;       // 0..383
                    int pos = (kk * 4 + quad) ^ (row & 7);
                    af[mt] = *(const bf16x8*)(As + (row * 8 + pos) * 16);
                }
#pragma unroll
                for (int nh = 0; nh < 2; ++nh) {
                    bf16x8 bfr[4];
#pragma unroll
                    for (int nt = 0; nt < 4; ++nt) {
                        int row = dy * 64 + wn * 128 + nh * 64 + nt * 16 + m15;  // 0..383
                        int pos = (kk * 4 + quad) ^ (row & 7);
                        bfr[nt] = *(const bf16x8*)(Bs + (row * 8 + pos) * 16);
                    }
#pragma unroll
                    for (int mt = 0; mt < 4; ++mt)
#pragma unroll
                        for (int nt = 0; nt < 4; ++nt)
                            acc[mt][nh * 4 + nt] = __builtin_amdgcn_mfma_f32_16x16x32_bf16(
                                af[mt], bfr[nt], acc[mt][nh * 4 + nt], 0, 0, 0);
                }
            }
    };

    stageA(0, SQh);      // Qh
    stageB(0, SKh);      // Kh
    stageB(128, SFl);    // Kl
    __syncthreads();
    runPair(SQh, SFl);   // Qh·Kl
    runPair(SQh, SKh);   // Qh·Kh
    __syncthreads();
    stageA(128, SFl);    // Ql overwrites Kl
    __syncthreads();
    runPair(SFl, SKh);   // Ql·Kh
    __syncthreads();     // slabs dead before epilogue overwrites

    // ---- epilogue: four 64-row phases; x-3sum + max/argmax over 256-k tile ----
    float* Csh = (float*)smem;               // [64][264]
    const int r = tid >> 3;                  // q row in band (0..63) == qx
    const int sub = tid & 7;                 // 32-col chunk
    const int c0s = sub * 32;
    const float4 zero4 = make_float4(0.f, 0.f, 0.f, 0.f);

#pragma unroll
    for (int h = 0; h < 4; ++h) {
        if (h) __syncthreads();
        if (wm == h) {
#pragma unroll
            for (int mt = 0; mt < 4; ++mt)
#pragma unroll
                for (int nn = 0; nn < 8; ++nn)
#pragma unroll
                    for (int j = 0; j < 4; ++j)
                        Csh[(mt * 16 + quad * 4 + j) * 264 +
                            wn * 128 + (nn >> 2) * 64 + (nn & 3) * 16 + m15] = acc[mt][nn][j];
        }
        __syncthreads();

        const bool qm = r > 0;               // qx>0: diag- allowed
        const bool qp = r < 63;              // qx<63: diag+ allowed
        const float* rC = Csh + r * 264;
        const float* rM = rC - 264;
        const float* rP = rC + 264;
        float4 prevm = (qm && c0s > 0) ? *(const float4*)&rM[c0s - 4] : zero4;
        float4 rpj   = qp ? *(const float4*)&rP[c0s] : zero4;
        float bv = -INFINITY;
        int ba = 0;
#pragma unroll
        for (int j = 0; j < 8; ++j) {
            int c = c0s + 4 * j;
            float4 cen = *(const float4*)&rC[c];
            float4 rm4 = qm ? *(const float4*)&rM[c] : zero4;
            float4 rp1 = (qp && (c + 4) < 256) ? *(const float4*)&rP[c + 4] : zero4;
            float4 o;
            o.x = cen.x + (((c & 63) != 0) ? prevm.w : 0.f) + rpj.y;
            o.y = cen.y + rm4.x + rpj.z;
            o.z = cen.z + rm4.y + rpj.w;
            o.w = cen.w + rm4.z + ((((c + 3) & 63) != 63) ? rp1.x : 0.f);
            float4 rk = *(const float4*)&rnkA[(b << 12) + k0 + c];
            // ascending k + strict > = first-occurrence argmax
            float v0 = o.x * rk.x; if (v0 > bv) { bv = v0; ba = k0 + c + 0; }
            float v1 = o.y * rk.y; if (v1 > bv) { bv = v1; ba = k0 + c + 1; }
            float v2 = o.z * rk.z; if (v2 > bv) { bv = v2; ba = k0 + c + 2; }
            float v3 = o.w * rk.w; if (v3 > bv) { bv = v3; ba = k0 + c + 3; }
            prevm = rm4;
            rpj = rp1;
        }
        // merge subs 0-3 / 4-7 (shfl over sub bits); lower k wins ties
        {
            float ov = __shfl_xor(bv, 1, 64);
            int oa = __shfl_xor(ba, 1, 64);
            if (ov > bv || (ov == bv && oa < ba)) { bv = ov; ba = oa; }
            ov = __shfl_xor(bv, 2, 64);
            oa = __shfl_xor(ba, 2, 64);
            if (ov > bv || (ov == bv && oa < ba)) { bv = ov; ba = oa; }
        }
        if ((sub & 3) == 0) {
            int q = q0 + h * 64 + r;
            int sidx = blockIdx.x * 2 + (sub >> 2);   // ascending-k slot order (32 slots/q)
            part_val[(((b << 5) + sidx) << 12) + q] = bv;
            part_arg[(((b << 5) + sidx) << 12) + q] = ba;
        }
    }
}

// ---------------- gather + fold, fused combine (32 k-slot partials) ----------
__global__ __launch_bounds__(256)
void gatherS_kernel(const float* __restrict__ V,
                    const float* __restrict__ part_val, const int* __restrict__ part_arg,
                    const float* __restrict__ rnqA,
                    float* __restrict__ S_out, float* __restrict__ T_out) {
    __shared__ int sArg[192];
    const int y = blockIdx.x, b = blockIdx.y;
    const int tid = threadIdx.x;
    if (tid < 192) {
        int r = tid >> 6, x = tid & 63;
        int yy = y - 1 + r;
        int a = 0;
        if ((unsigned)yy < 64u) {
            int base = (b << 17) + (yy << 6) + x;   // part[(b*32+s)][q]
            float bv = -INFINITY; int ba = 0;
#pragma unroll 8
            for (int s = 0; s < 32; ++s) {   // ascending s = ascending k: first max wins
                float v = part_val[base + (s << 12)];
                int aa = part_arg[base + (s << 12)];
                if (v > bv) { bv = v; ba = aa; }
            }
            a = ba;
            if (r == 1) {
                int idx = (b << 12) + (yy << 6) + x;
                S_out[idx] = bv * rnqA[idx];
            }
        }
        sArg[tid] = a;
    }
    __syncthreads();

    const int x = tid & 63, cq = tid >> 6;
    int off[9];
#pragma unroll
    for (int t = 0; t < 9; ++t) {
        int dy = t / 3 - 1, dx = t % 3 - 1;
        int qy = y - dy, qx = x - dx;
        int o = -1;
        if ((unsigned)qy < 64u && (unsigned)qx < 64u) {
            int a = sArg[(1 - dy) * 64 + qx];
            int sy = (a >> 6) + dy, sx = (a & 63) + dx;
            if ((unsigned)sy < 64u && (unsigned)sx < 64u) o = (sy << 6) + sx;
        }
        off[t] = o;
    }
    const float* Vb = V + (size_t)b * 64 * HW;
    float* Tb = T_out + (size_t)b * 64 * HW + (y << 6) + x;
    for (int ci = 0; ci < 16; ++ci) {
        int c = cq * 16 + ci;
        const float* Vc = Vb + (size_t)c * HW;
        float acc = 0.f;
#pragma unroll
        for (int t = 0; t < 9; ++t)
            acc += (off[t] >= 0) ? Vc[off[t]] : 0.f;
        Tb[(size_t)c * HW] = acc * (1.f / 9.f);
    }
}

extern "C" void kernel_launch(void* const* d_in, const int* in_sizes, int n_in,
                              void* d_out, int out_size, void* d_ws, size_t ws_size,
                              hipStream_t stream) {
    const float* V = (const float*)d_in[0];
    const float* K = (const float*)d_in[1];
    const float* Q = (const float*)d_in[2];
    float* S_out = (float*)d_out;            // 4*4096
    float* T_out = S_out + 4 * HW;           // 4*64*4096

    char* ws = (char*)d_ws;
    float* pix2q = (float*)(ws + 0);                 // 64 KB
    float* pix2k = (float*)(ws + 65536);
    float* rnq   = (float*)(ws + 131072);
    float* rnk   = (float*)(ws + 196608);
    float* part_val = (float*)(ws + 262144);         // 4*32*4096 f = 2 MB
    int*   part_arg = (int*)(ws + 2359296);          // 2 MB
    unsigned short* Aq = (unsigned short*)(ws + 4456448);    // 4*4096*128 bf16 = 4 MiB
    unsigned short* Bq = (unsigned short*)(ws + 8650752);    // 4 MiB

    prep_kernel<<<dim3(64, 4), 256, 0, stream>>>(Q, K, Aq, Bq, pix2q, pix2k);
    patchnorm_kernel<<<64, 256, 0, stream>>>(pix2q, pix2k, rnq, rnk);
    gemm_fused_kernel<<<dim3(16, 16, 4), 512, 0, stream>>>(Aq, Bq, rnk, part_val, part_arg);
    gatherS_kernel<<<dim3(64, 4), 256, 0, stream>>>(V, part_val, part_arg, rnq, S_out, T_out);
}